// Round 6
// baseline (101.699 us; speedup 1.0000x reference)
//
#include <hip/hip_runtime.h>
#include <stdint.h>
#include <stddef.h>

#define BB 16384
#define CC 500
#define DD 512
#define PADC 512
#define LMARGIN 1.0f
#define EPSQ 1e-12f
#define NK 16  // K-chunks of 32

typedef __attribute__((ext_vector_type(8))) _Float16 f16x8;
typedef __attribute__((ext_vector_type(4))) _Float16 f16x4;
typedef __attribute__((ext_vector_type(4))) float f32x4;

// ---- prep P: prototypes fp32 -> f16 row-major [c][k] (zero-padded to 512
// rows), p2[] fp32, zero the output accumulator ----
__global__ void prepP_kernel(const float* __restrict__ protos,
                             unsigned short* __restrict__ protoH,
                             float* __restrict__ p2,
                             float* __restrict__ out) {
  int c = blockIdx.x * 4 + (threadIdx.x >> 6);  // 0..511
  int lane = threadIdx.x & 63;
  if (c == 0 && lane == 0) out[0] = 0.f;
  f32x4 a0 = {0.f, 0.f, 0.f, 0.f}, a1 = a0;
  if (c < CC) {
    const float* src = protos + (size_t)c * DD + lane * 8;
    a0 = *(const f32x4*)src;
    a1 = *(const f32x4*)(src + 4);
  }
  f16x8 h;
  float s = 0.f;
#pragma unroll
  for (int u = 0; u < 4; ++u) {
    h[u] = (_Float16)a0[u];
    h[u + 4] = (_Float16)a1[u];
    s = fmaf(a0[u], a0[u], s);
    s = fmaf(a1[u], a1[u], s);
  }
  *(f16x8*)(protoH + (size_t)c * DD + lane * 8) = h;
#pragma unroll
  for (int d = 1; d < 64; d <<= 1) s += __shfl_xor(s, d, 64);
  if (lane == 0) p2[c] = s;
}

// ---- main kernel: 256 blocks x 512 threads (8 waves).
// Block = 64 rows x 512 padded cols. Wave w owns ALL 64 rows x 64 cols.
// A: fp32 -> f16 LDS once in prologue (64 KB, the only __shared__).
// B: direct global->VGPR fragments, prefetched 1 kc ahead. K-loop has NO
// barriers and NO LDS writes. Epilogue reduces q = p2 - 2*dot per
// (row, octant) to ws2; f2 per row to f2ws (sqrt/hinge in reduce_kernel;
// valid since sqrt(max(f2+q,eps)) is monotone in q). ----
__launch_bounds__(512, 2)
__global__ void main_kernel(const float* __restrict__ feat,
                            const unsigned short* __restrict__ protoH,
                            const float* __restrict__ p2,
                            const int* __restrict__ labels,
                            float* __restrict__ f2ws,
                            float2* __restrict__ ws2) {
  // A, k-chunked: [kc][row][32 k] f16. Frag/write addresses are bank-balanced.
  __shared__ __align__(16) unsigned short Afull[NK][64][32];  // 64 KB exactly

  const int tid = threadIdx.x;
  const int w = tid >> 6;
  const int lane = tid & 63;
  const int lane16 = lane & 15;
  const int quad = lane >> 4;
  const int r0 = blockIdx.x * 64;

  // ---- B fragment base: col = w*64 + nt*16 + lane16, k = kc*32 + quad*8 ----
  const unsigned short* pb = protoH + (size_t)(w * 64 + lane16) * DD + quad * 8;

  // ---- issue B kc=0 prefetch before the A prologue ----
  f16x8 bcur[4], bnxt[4];
#pragma unroll
  for (int nt = 0; nt < 4; ++nt) bcur[nt] = *(const f16x8*)(pb + nt * 16 * DD);

  // ---- A prologue: flat-coalesced fp32 loads, cvt, ds_write; f2 per row ----
  // f4 index = w*1024 + i*64 + lane  ->  row = w*8 + (i>>1) (wave-uniform per
  // i), k = (i&1)*256 + lane*4. Each wave owns rows w*8..w*8+7.
  {
    const f32x4* fsrc = (const f32x4*)(feat + (size_t)r0 * DD);
    f32x4 a[NK];
#pragma unroll
    for (int i = 0; i < NK; ++i) a[i] = fsrc[w * 1024 + i * 64 + lane];

    float f2row[8] = {0.f, 0.f, 0.f, 0.f, 0.f, 0.f, 0.f, 0.f};
#pragma unroll
    for (int i = 0; i < NK; ++i) {
      const int row = w * 8 + (i >> 1);
      const int k = (i & 1) * 256 + lane * 4;
      f16x4 h;
      float s = 0.f;
#pragma unroll
      for (int u = 0; u < 4; ++u) {
        h[u] = (_Float16)a[i][u];
        s = fmaf(a[i][u], a[i][u], s);
      }
      *(f16x4*)(&Afull[k >> 5][row][k & 31]) = h;
#pragma unroll
      for (int d = 1; d < 64; d <<= 1) s += __shfl_xor(s, d, 64);
      f2row[i >> 1] += s;
    }
    if (lane == 0) {
#pragma unroll
      for (int j = 0; j < 8; ++j) f2ws[r0 + w * 8 + j] = f2row[j];
    }
  }

  f32x4 acc[4][4];
#pragma unroll
  for (int mt = 0; mt < 4; ++mt)
#pragma unroll
    for (int nt = 0; nt < 4; ++nt) acc[mt][nt] = (f32x4){0.f, 0.f, 0.f, 0.f};

  __syncthreads();  // A staged (the only barrier in this kernel)

  // ---- K-loop: no barriers, no LDS writes; B prefetched 1 kc ahead ----
#pragma unroll 2
  for (int kc = 0; kc < NK; ++kc) {
    if (kc + 1 < NK) {
#pragma unroll
      for (int nt = 0; nt < 4; ++nt)
        bnxt[nt] = *(const f16x8*)(pb + nt * 16 * DD + (kc + 1) * 32);
    }
    f16x8 af[4];
#pragma unroll
    for (int mt = 0; mt < 4; ++mt)
      af[mt] = *(const f16x8*)(&Afull[kc][mt * 16 + lane16][0] + quad * 8);
#pragma unroll
    for (int mt = 0; mt < 4; ++mt)
#pragma unroll
      for (int nt = 0; nt < 4; ++nt)
        acc[mt][nt] = __builtin_amdgcn_mfma_f32_16x16x32_f16(
            af[mt], bcur[nt], acc[mt][nt], 0, 0, 0);
#pragma unroll
    for (int nt = 0; nt < 4; ++nt) bcur[nt] = bnxt[nt];
  }

  // ---- epilogue: q = p2 - 2*dot; masked min (negs) / max (pos) over my 64
  // cols; write per-(row, octant) pair. No f2, no sqrt here. ----
  float p2v[4];
#pragma unroll
  for (int nt = 0; nt < 4; ++nt) p2v[nt] = p2[w * 64 + nt * 16 + lane16];

#pragma unroll
  for (int mt = 0; mt < 4; ++mt) {
#pragma unroll
    for (int i = 0; i < 4; ++i) {
      const int row = mt * 16 + quad * 4 + i;
      const int lb = labels[r0 + row];  // broadcast load
      float qm = 1e30f, qp = -1e30f;
#pragma unroll
      for (int nt = 0; nt < 4; ++nt) {
        const int col = w * 64 + nt * 16 + lane16;
        float q = p2v[nt] - 2.f * acc[mt][nt][i];
        bool isPos = (col == lb);
        qp = fmaxf(qp, isPos ? q : -1e30f);
        qm = fminf(qm, (!isPos && col < CC) ? q : 1e30f);
      }
#pragma unroll
      for (int d = 1; d < 16; d <<= 1) {
        qm = fminf(qm, __shfl_xor(qm, d, 64));
        qp = fmaxf(qp, __shfl_xor(qp, d, 64));
      }
      if (lane16 == 0) ws2[(size_t)(r0 + row) * 8 + w] = make_float2(qm, qp);
    }
  }
}

// ---- final: combine 8 octants per row, f2 + sqrt + hinge, mean ----
__global__ void reduce_kernel(const float2* __restrict__ ws2,
                              const float* __restrict__ f2ws,
                              float* __restrict__ out) {
  int row = blockIdx.x * 256 + threadIdx.x;
  const float4* v = (const float4*)ws2;  // (q0,p0,q1,p1) per float4
  float qm = 1e30f, qp = -1e30f;
#pragma unroll
  for (int j = 0; j < 4; ++j) {
    float4 a = v[(size_t)row * 4 + j];
    qm = fminf(qm, fminf(a.x, a.z));
    qp = fmaxf(qp, fmaxf(a.y, a.w));
  }
  float f2 = f2ws[row];
  float dn = sqrtf(fmaxf(f2 + qm, EPSQ));
  float dp = sqrtf(fmaxf(f2 + qp, EPSQ));
  float term = fmaxf(dp - dn + LMARGIN, 0.f);
#pragma unroll
  for (int d = 1; d < 64; d <<= 1) term += __shfl_xor(term, d, 64);
  __shared__ float ws4[4];
  if ((threadIdx.x & 63) == 0) ws4[threadIdx.x >> 6] = term;
  __syncthreads();
  if (threadIdx.x == 0)
    atomicAdd(out, (ws4[0] + ws4[1] + ws4[2] + ws4[3]) * (1.0f / BB));
}

extern "C" void kernel_launch(void* const* d_in, const int* in_sizes, int n_in,
                              void* d_out, int out_size, void* d_ws, size_t ws_size,
                              hipStream_t stream) {
  const float* feat = (const float*)d_in[0];
  const float* protos = (const float*)d_in[1];
  const int* labels = (const int*)d_in[2];
  float* out = (float*)d_out;

  char* ws = (char*)d_ws;
  unsigned short* protoH = (unsigned short*)(ws);        // 512 KB @ 0
  float* p2 = (float*)(ws + (512 << 10));                // 2 KB
  float* f2ws = (float*)(ws + (1 << 20));                // 64 KB
  float2* ws2 = (float2*)(ws + (2 << 20));               // 1 MB

  prepP_kernel<<<PADC / 4, 256, 0, stream>>>(protos, protoH, p2, out);
  main_kernel<<<BB / 64, 512, 0, stream>>>(feat, protoH, p2, labels, f2ws, ws2);
  reduce_kernel<<<BB / 256, 256, 0, stream>>>(ws2, f2ws, out);
}

// Round 7
// 93.615 us; speedup vs baseline: 1.0864x; 1.0864x over previous
//
#include <hip/hip_runtime.h>
#include <stdint.h>
#include <stddef.h>

#define BB 16384
#define CC 500
#define DD 512
#define PADC 512
#define LMARGIN 1.0f
#define EPSQ 1e-12f
#define NK 16  // K-chunks of 32

typedef __attribute__((ext_vector_type(8))) _Float16 f16x8;
typedef __attribute__((ext_vector_type(4))) _Float16 f16x4;
typedef __attribute__((ext_vector_type(4))) float f32x4;

// ---- prepP: protos fp32 -> protoT f16 in FRAGMENT-LINEAR layout + p2 ----
// protoT byte layout: unit (cg, kc) at offset (cg*16 + kc)*1024; within the
// 1KB unit, lane l's 16 bytes = B[col = cg*16 + (l&15)][k = kc*32 + (l>>4)*8
// .. +7]. A wave's B-fragment load is then one contiguous 1KB dwordx4.
__global__ void prepP_kernel(const float* __restrict__ protos,
                             unsigned short* __restrict__ protoT,
                             float* __restrict__ p2,
                             float* __restrict__ out) {
  __shared__ float s_arr[16][17];
  const int cg = blockIdx.x;   // 0..31
  const int t = threadIdx.x;   // 0..255
  const int colin = t & 15;
  const int jb = t >> 4;       // 0..15
  const int col = cg * 16 + colin;
  if (cg == 0 && t == 0) out[0] = 0.f;
  float s = 0.f;
#pragma unroll
  for (int u = 0; u < 4; ++u) {
    const int j8 = jb + u * 16;          // 0..63: 8-float k-unit
    const int kc = j8 >> 2, quad = j8 & 3;
    f32x4 a0 = {0.f, 0.f, 0.f, 0.f}, a1 = a0;
    if (col < CC) {
      const float* src = protos + (size_t)col * DD + j8 * 8;
      a0 = *(const f32x4*)src;
      a1 = *(const f32x4*)(src + 4);
    }
    f16x8 h;
#pragma unroll
    for (int uu = 0; uu < 4; ++uu) {
      h[uu] = (_Float16)a0[uu];
      h[uu + 4] = (_Float16)a1[uu];
      s = fmaf(a0[uu], a0[uu], s);
      s = fmaf(a1[uu], a1[uu], s);
    }
    *(f16x8*)(protoT + (size_t)(cg * 16 + kc) * 512 + (quad * 16 + colin) * 8) = h;
  }
  s_arr[colin][jb] = s;
  __syncthreads();
  if (t < 16) {
    float acc = 0.f;
#pragma unroll
    for (int i = 0; i < 16; ++i) acc += s_arr[t][i];
    p2[cg * 16 + t] = acc;
  }
}

// ---- main: 256 blocks x 512 threads (8 waves). Block = 64 rows x 512 cols;
// wave w = col-octant (64 cols) x all 64 rows; acc 4x4 of 16x16x32.
// A: fp32 global -> cvt -> XOR-swizzled LDS, 3-slot ring, staged inside the
// K-loop (HBM stream overlaps MFMA). B: fragment-linear global->VGPR,
// contiguous 1KB loads, 2-kc prefetch, no LDS. Hinge completes in-block. ----
__launch_bounds__(512, 2)
__global__ void main_kernel(const float* __restrict__ feat,
                            const unsigned short* __restrict__ protoT,
                            const float* __restrict__ p2,
                            const int* __restrict__ labels,
                            float* __restrict__ out) {
  __shared__ __align__(16) unsigned char Ab[3][4096];  // A ring, 12 KB
  __shared__ float f2l[64];

  const int tid = threadIdx.x;
  const int w = tid >> 6;
  const int lane = tid & 63;
  const int lane16 = lane & 15;
  const int quad = lane >> 4;
  const int r0 = blockIdx.x * 64;

  // epilogue scratch aliased onto ring slot 1 (stale after the K-loop)
  float* redM = (float*)&Ab[1][0];     // [64 rows][8 w]
  float* redP = (float*)&Ab[1][2048];  // [64 rows][8 w]

  // ---- A staging mapping: thread -> (row, 16B k-chunk half) ----
  const int arow = tid >> 3;          // 0..63
  const int aj = tid & 7;             // which 4-float unit of the 32-float kc
  const float* aSrc = feat + (size_t)(r0 + arow) * DD + aj * 4;
  // LDS write offset with XOR swizzle: chunk j = aj>>1 stored at j ^ ((row>>1)&3)
  const int awoff = arow * 64 + (((aj >> 1) ^ ((arow >> 1) & 3)) * 16) + (aj & 1) * 8;
  // A fragment read offset (mt-independent part): row = lane16 (+16*mt handled
  // by +1024*mt), chunk quad stored at quad ^ ((row>>1)&3)
  const int aroff = lane16 * 64 + ((quad ^ ((lane16 >> 1) & 3)) * 16);

  // ---- B pointers: unit (cg = w*4+nt, kc) at byte (cg*16+kc)*1024 ----
  const char* bptr[4];
#pragma unroll
  for (int nt = 0; nt < 4; ++nt)
    bptr[nt] = (const char*)protoT + (size_t)((w * 4 + nt) * 16) * 1024 + lane * 16;

  f32x4 acc[4][4];
#pragma unroll
  for (int mt = 0; mt < 4; ++mt)
#pragma unroll
    for (int nt = 0; nt < 4; ++nt) acc[mt][nt] = (f32x4){0.f, 0.f, 0.f, 0.f};

  float f2acc = 0.f;
  f16x8 bfr[3][4];
  f32x4 aC;  // A fp32 pending cvt+write (for kc+2 at iter kc)

  // ---- prologue: A(0)->slot0, A(1)->slot1 (cvt+write), A(2) in flight;
  //      B(0)->bfr[0], B(1)->bfr[1] ----
  {
    f32x4 a0 = *(const f32x4*)(aSrc);
    f32x4 a1 = *(const f32x4*)(aSrc + 32);
    aC = *(const f32x4*)(aSrc + 64);
#pragma unroll
    for (int nt = 0; nt < 4; ++nt) {
      bfr[0][nt] = *(const f16x8*)(bptr[nt]);
      bfr[1][nt] = *(const f16x8*)(bptr[nt] + 1024);
    }
    f16x4 h0, h1;
#pragma unroll
    for (int u = 0; u < 4; ++u) {
      h0[u] = (_Float16)a0[u];
      h1[u] = (_Float16)a1[u];
      f2acc = fmaf(a0[u], a0[u], f2acc);
      f2acc = fmaf(a1[u], a1[u], f2acc);
    }
    *(f16x4*)(&Ab[0][awoff]) = h0;
    *(f16x4*)(&Ab[1][awoff]) = h1;
  }
  __syncthreads();

  // ---- K-loop: fully unrolled; one barrier per kc ----
#pragma unroll
  for (int kc = 0; kc < NK; ++kc) {
    f32x4 aN;
    if (kc + 3 < NK) aN = *(const f32x4*)(aSrc + (kc + 3) * 32);  // issue first
    if (kc + 2 < NK) {
#pragma unroll
      for (int nt = 0; nt < 4; ++nt)
        bfr[(kc + 2) % 3][nt] = *(const f16x8*)(bptr[nt] + (kc + 2) * 1024);
    }

    f16x8 af[4];
#pragma unroll
    for (int mt = 0; mt < 4; ++mt)
      af[mt] = *(const f16x8*)(&Ab[kc % 3][mt * 1024 + aroff]);
#pragma unroll
    for (int mt = 0; mt < 4; ++mt)
#pragma unroll
      for (int nt = 0; nt < 4; ++nt)
        acc[mt][nt] = __builtin_amdgcn_mfma_f32_16x16x32_f16(
            af[mt], bfr[kc % 3][nt], acc[mt][nt], 0, 0, 0);

    if (kc + 2 < NK) {
      // cvt + swizzled write of A(kc+2) (fp32 loaded at iter kc-1)
      f16x4 h;
#pragma unroll
      for (int u = 0; u < 4; ++u) {
        h[u] = (_Float16)aC[u];
        f2acc = fmaf(aC[u], aC[u], f2acc);
      }
      *(f16x4*)(&Ab[(kc + 2) % 3][awoff]) = h;
      aC = aN;
    }
    __syncthreads();
  }

  // ---- f2 per row: 8 consecutive threads share a row ----
  f2acc += __shfl_xor(f2acc, 1, 64);
  f2acc += __shfl_xor(f2acc, 2, 64);
  f2acc += __shfl_xor(f2acc, 4, 64);
  if ((tid & 7) == 0) f2l[arow] = f2acc;

  // ---- epilogue: q = p2 - 2*dot, masked min/pos over my 64 cols ----
  float p2v[4];
#pragma unroll
  for (int nt = 0; nt < 4; ++nt) p2v[nt] = p2[w * 64 + nt * 16 + lane16];

#pragma unroll
  for (int mt = 0; mt < 4; ++mt) {
#pragma unroll
    for (int i = 0; i < 4; ++i) {
      const int row = mt * 16 + quad * 4 + i;
      const int lb = labels[r0 + row];  // wave-broadcast load
      float qm = 1e30f, qp = -1e30f;
#pragma unroll
      for (int nt = 0; nt < 4; ++nt) {
        const int col = w * 64 + nt * 16 + lane16;
        float q = p2v[nt] - 2.f * acc[mt][nt][i];
        bool isPos = (col == lb);
        qp = fmaxf(qp, isPos ? q : -1e30f);
        qm = fminf(qm, (!isPos && col < CC) ? q : 1e30f);
      }
#pragma unroll
      for (int d = 1; d < 16; d <<= 1) {
        qm = fminf(qm, __shfl_xor(qm, d, 64));
        qp = fmaxf(qp, __shfl_xor(qp, d, 64));
      }
      if (lane16 == 0) {
        redM[row * 8 + w] = qm;
        redP[row * 8 + w] = qp;
      }
    }
  }
  __syncthreads();

  // ---- combine 8 octants per row, sqrt+hinge, block sum, one atomic ----
  if (tid < 64) {
    float qm = 1e30f, qp = -1e30f;
#pragma unroll
    for (int j = 0; j < 8; ++j) {
      qm = fminf(qm, redM[tid * 8 + j]);
      qp = fmaxf(qp, redP[tid * 8 + j]);
    }
    float f2 = f2l[tid];
    float dn = sqrtf(fmaxf(f2 + qm, EPSQ));
    float dp = sqrtf(fmaxf(f2 + qp, EPSQ));
    float term = fmaxf(dp - dn + LMARGIN, 0.f);
#pragma unroll
    for (int d = 1; d < 64; d <<= 1) term += __shfl_xor(term, d, 64);
    if (tid == 0) atomicAdd(out, term * (1.0f / BB));
  }
}

extern "C" void kernel_launch(void* const* d_in, const int* in_sizes, int n_in,
                              void* d_out, int out_size, void* d_ws, size_t ws_size,
                              hipStream_t stream) {
  const float* feat = (const float*)d_in[0];
  const float* protos = (const float*)d_in[1];
  const int* labels = (const int*)d_in[2];
  float* out = (float*)d_out;

  char* ws = (char*)d_ws;
  unsigned short* protoT = (unsigned short*)(ws);   // 512 KB fragment-linear B
  float* p2 = (float*)(ws + (512 << 10));           // 2 KB

  prepP_kernel<<<32, 256, 0, stream>>>(protos, protoT, p2, out);
  main_kernel<<<BB / 64, 512, 0, stream>>>(feat, protoT, p2, labels, out);
}

// Round 8
// 93.132 us; speedup vs baseline: 1.0920x; 1.0052x over previous
//
#include <hip/hip_runtime.h>
#include <stdint.h>
#include <stddef.h>

#define BB 16384
#define CC 500
#define DD 512
#define PADC 512
#define LMARGIN 1.0f
#define EPSQ 1e-12f
#define NK 16  // K-chunks of 32

typedef __attribute__((ext_vector_type(8))) _Float16 f16x8;
typedef __attribute__((ext_vector_type(4))) _Float16 f16x4;
typedef __attribute__((ext_vector_type(4))) float f32x4;

// ---- prepP: protos fp32 -> protoT f16 in FRAGMENT-LINEAR layout + p2 ----
// protoT byte layout: unit (cg, kc) at offset (cg*16 + kc)*1024; within the
// 1KB unit, lane l's 16 bytes = B[col = cg*16 + (l&15)][k = kc*32 + (l>>4)*8
// .. +7]. A wave's B-fragment load is then one contiguous 1KB dwordx4.
__global__ void prepP_kernel(const float* __restrict__ protos,
                             unsigned short* __restrict__ protoT,
                             float* __restrict__ p2,
                             float* __restrict__ out) {
  __shared__ float s_arr[16][17];
  const int cg = blockIdx.x;   // 0..31
  const int t = threadIdx.x;   // 0..255
  const int colin = t & 15;
  const int jb = t >> 4;       // 0..15
  const int col = cg * 16 + colin;
  if (cg == 0 && t == 0) out[0] = 0.f;
  float s = 0.f;
#pragma unroll
  for (int u = 0; u < 4; ++u) {
    const int j8 = jb + u * 16;          // 0..63: 8-float k-unit
    const int kc = j8 >> 2, quad = j8 & 3;
    f32x4 a0 = {0.f, 0.f, 0.f, 0.f}, a1 = a0;
    if (col < CC) {
      const float* src = protos + (size_t)col * DD + j8 * 8;
      a0 = *(const f32x4*)src;
      a1 = *(const f32x4*)(src + 4);
    }
    f16x8 h;
#pragma unroll
    for (int uu = 0; uu < 4; ++uu) {
      h[uu] = (_Float16)a0[uu];
      h[uu + 4] = (_Float16)a1[uu];
      s = fmaf(a0[uu], a0[uu], s);
      s = fmaf(a1[uu], a1[uu], s);
    }
    *(f16x8*)(protoT + (size_t)(cg * 16 + kc) * 512 + (quad * 16 + colin) * 8) = h;
  }
  s_arr[colin][jb] = s;
  __syncthreads();
  if (t < 16) {
    float acc = 0.f;
#pragma unroll
    for (int i = 0; i < 16; ++i) acc += s_arr[t][i];
    p2[cg * 16 + t] = acc;
  }
}

// ---- main: 256 blocks x 512 threads (8 waves). Block = 64 rows x 512 cols;
// wave w = col-octant (64 cols) x all 64 rows; acc 4x4 of 16x16x32.
// A: full 64x512 tile fp32->f16 into XOR-swizzled LDS in the PROLOGUE (the
// only HBM phase; 2 batches of 8 coalesced f32x4 per thread). K-loop is
// BARRIER-FREE: A from LDS (conflict-free swizzle), B fragment-linear
// global->VGPR (contiguous 1KB loads, ring-3/depth-2 prefetch, L2-resident).
// Exactly 2 __syncthreads in the kernel. Hinge completes in-block. ----
__launch_bounds__(512, 2)
__global__ void main_kernel(const float* __restrict__ feat,
                            const unsigned short* __restrict__ protoT,
                            const float* __restrict__ p2,
                            const int* __restrict__ labels,
                            float* __restrict__ out) {
  __shared__ __align__(16) unsigned char Afull[NK * 4096];  // 64 KB
  __shared__ float p2l[PADC];
  __shared__ float f2l[64];
  __shared__ int labl[64];
  __shared__ float redM[64 * 8], redP[64 * 8];

  const int tid = threadIdx.x;
  const int w = tid >> 6;
  const int lane = tid & 63;
  const int lane16 = lane & 15;
  const int quad = lane >> 4;
  const int r0 = blockIdx.x * 64;

  // ---- B pointers: unit (cg = w*4+nt, kc) at byte (w*64 + nt*16 + kc)*1024 ----
  const char* bptr[4];
#pragma unroll
  for (int nt = 0; nt < 4; ++nt)
    bptr[nt] = (const char*)protoT + (size_t)(w * 64 + nt * 16) * 1024 + lane * 16;

  // issue B(0), B(1) early (L2; retire during the A prologue)
  f16x8 bfr[3][4];
#pragma unroll
  for (int nt = 0; nt < 4; ++nt) {
    bfr[0][nt] = *(const f16x8*)(bptr[nt]);
    bfr[1][nt] = *(const f16x8*)(bptr[nt] + 1024);
  }

  // ---- A prologue: thread (arow = tid>>3, aj = tid&7) stages row arow's
  // floats [kc*32 + aj*4 .. +3] for all kc; XOR-swizzled 16B chunks ----
  const int arow = tid >> 3;
  const int aj = tid & 7;
  const float* aSrc = feat + (size_t)(r0 + arow) * DD + aj * 4;
  const int awbase =
      arow * 64 + (((aj >> 1) ^ ((arow >> 1) & 3)) * 16) + (aj & 1) * 8;

  float s = 0.f;
  {
    f32x4 av0[8], av1[8];
#pragma unroll
    for (int i = 0; i < 8; ++i) av0[i] = *(const f32x4*)(aSrc + i * 32);
#pragma unroll
    for (int i = 0; i < 8; ++i) av1[i] = *(const f32x4*)(aSrc + (8 + i) * 32);
#pragma unroll
    for (int i = 0; i < 8; ++i) {
      f16x4 h;
#pragma unroll
      for (int u = 0; u < 4; ++u) {
        h[u] = (_Float16)av0[i][u];
        s = fmaf(av0[i][u], av0[i][u], s);
      }
      *(f16x4*)(&Afull[i * 4096 + awbase]) = h;
    }
#pragma unroll
    for (int i = 0; i < 8; ++i) {
      f16x4 h;
#pragma unroll
      for (int u = 0; u < 4; ++u) {
        h[u] = (_Float16)av1[i][u];
        s = fmaf(av1[i][u], av1[i][u], s);
      }
      *(f16x4*)(&Afull[(8 + i) * 4096 + awbase]) = h;
    }
  }
  // f2 for row arow: 8 consecutive lanes (aj 0..7) share it
  s += __shfl_xor(s, 1, 64);
  s += __shfl_xor(s, 2, 64);
  s += __shfl_xor(s, 4, 64);
  if ((lane & 7) == 0) f2l[arow] = s;

  p2l[tid] = p2[tid];
  if (tid < 64) labl[tid] = labels[r0 + tid];

  f32x4 acc[4][4];
#pragma unroll
  for (int mt = 0; mt < 4; ++mt)
#pragma unroll
    for (int nt = 0; nt < 4; ++nt) acc[mt][nt] = (f32x4){0.f, 0.f, 0.f, 0.f};

  __syncthreads();  // barrier #1: A tile + scalars staged

  // ---- K-loop: NO barriers, no LDS writes, no HBM. B depth-2 prefetch. ----
  const int aroff = lane16 * 64 + ((quad ^ ((lane16 >> 1) & 3)) * 16);
#pragma unroll
  for (int kc = 0; kc < NK; ++kc) {
    if (kc + 2 < NK) {
#pragma unroll
      for (int nt = 0; nt < 4; ++nt)
        bfr[(kc + 2) % 3][nt] = *(const f16x8*)(bptr[nt] + (kc + 2) * 1024);
    }
    f16x8 af[4];
#pragma unroll
    for (int mt = 0; mt < 4; ++mt)
      af[mt] = *(const f16x8*)(&Afull[kc * 4096 + mt * 1024 + aroff]);
#pragma unroll
    for (int mt = 0; mt < 4; ++mt)
#pragma unroll
      for (int nt = 0; nt < 4; ++nt)
        acc[mt][nt] = __builtin_amdgcn_mfma_f32_16x16x32_f16(
            af[mt], bfr[kc % 3][nt], acc[mt][nt], 0, 0, 0);
  }

  // ---- epilogue: q = p2 - 2*dot; masked min/pos over my 64 cols ----
  float p2v[4];
#pragma unroll
  for (int nt = 0; nt < 4; ++nt) p2v[nt] = p2l[w * 64 + nt * 16 + lane16];

#pragma unroll
  for (int mt = 0; mt < 4; ++mt) {
#pragma unroll
    for (int i = 0; i < 4; ++i) {
      const int row = mt * 16 + quad * 4 + i;
      const int lb = labl[row];
      float qm = 1e30f, qp = -1e30f;
#pragma unroll
      for (int nt = 0; nt < 4; ++nt) {
        const int col = w * 64 + nt * 16 + lane16;
        float q = p2v[nt] - 2.f * acc[mt][nt][i];
        bool isPos = (col == lb);
        qp = fmaxf(qp, isPos ? q : -1e30f);
        qm = fminf(qm, (!isPos && col < CC) ? q : 1e30f);
      }
#pragma unroll
      for (int d = 1; d < 16; d <<= 1) {
        qm = fminf(qm, __shfl_xor(qm, d, 64));
        qp = fmaxf(qp, __shfl_xor(qp, d, 64));
      }
      if (lane16 == 0) {
        redM[row * 8 + w] = qm;
        redP[row * 8 + w] = qp;
      }
    }
  }
  __syncthreads();  // barrier #2: partials visible

  // ---- combine 8 octants per row, sqrt+hinge, block sum, one atomic ----
  if (tid < 64) {
    float qm = 1e30f, qp = -1e30f;
#pragma unroll
    for (int j = 0; j < 8; ++j) {
      qm = fminf(qm, redM[tid * 8 + j]);
      qp = fmaxf(qp, redP[tid * 8 + j]);
    }
    float f2 = f2l[tid];
    float dn = sqrtf(fmaxf(f2 + qm, EPSQ));
    float dp = sqrtf(fmaxf(f2 + qp, EPSQ));
    float term = fmaxf(dp - dn + LMARGIN, 0.f);
#pragma unroll
    for (int d = 1; d < 64; d <<= 1) term += __shfl_xor(term, d, 64);
    if (tid == 0) atomicAdd(out, term * (1.0f / BB));
  }
}

extern "C" void kernel_launch(void* const* d_in, const int* in_sizes, int n_in,
                              void* d_out, int out_size, void* d_ws, size_t ws_size,
                              hipStream_t stream) {
  const float* feat = (const float*)d_in[0];
  const float* protos = (const float*)d_in[1];
  const int* labels = (const int*)d_in[2];
  float* out = (float*)d_out;

  char* ws = (char*)d_ws;
  unsigned short* protoT = (unsigned short*)(ws);   // 512 KB fragment-linear B
  float* p2 = (float*)(ws + (512 << 10));           // 2 KB

  prepP_kernel<<<32, 256, 0, stream>>>(protos, protoT, p2, out);
  main_kernel<<<BB / 64, 512, 0, stream>>>(feat, protoT, p2, labels, out);
}